// Round 5
// baseline (512.396 us; speedup 1.0000x reference)
//
#include <hip/hip_runtime.h>
#include <math.h>

// Problem constants (from reference)
#define NM 20301          // mesh points (201*202/2)
#define TT 4096           // time steps
#define NC 16             // chunks over T
#define CH 256            // steps per chunk = TT/NC
#define NBLK 80           // ceil(NM/256)
#define NWAVE 4           // waves per block
#define NPAR (NBLK*NWAVE) // 320 partial rows
#define TPH 16            // t-phase width (16 -> 18.4KB LDS -> 8 blocks/CU)
#define NPH (CH / TPH)    // 16 phases per chunk
#define LOG2E_K 1442.69504f   // 1000 * log2(e)  (temp = 0.001)

// Fused soft-relay step: up=1/(1+e1), dn=1/(1+e2) computed with ONE rcp:
//   r  = rcp((1+e1)(1+e2));  aa = up-dn = (e2-e1)*r;  bb = (1-up)(1-dn) = e1*e2*r
// exp2 args clamped at 63 so all products stay finite (saturation limits exact).
__device__ __forceinline__ void relay_step(float ka, float kb, float ku,
                                           float& aa, float& bb) {
    float z1 = fminf(ka - ku, 63.f);
    float z2 = fminf(ku - kb, 63.f);
    float e1 = __builtin_amdgcn_exp2f(z1);
    float e2 = __builtin_amdgcn_exp2f(z2);
    float p1 = 1.f + e1, p2 = 1.f + e2;
    float r  = __builtin_amdgcn_rcpf(p1 * p2);
    aa = (e2 - e1) * r;
    bb = (e1 * e2) * r;
}

__device__ __forceinline__ float wave_reduce_sum(float w) {
    #pragma unroll
    for (int off = 32; off > 0; off >>= 1)
        w += __shfl_down(w, off, 64);
    return w;
}

// ---------------- density MLP: [N,2] -> 16 -> 16 -> 16 -> 1 ----------------
__global__ __launch_bounds__(256) void density_kernel(
    const float* __restrict__ alpha, const float* __restrict__ beta,
    const float* __restrict__ w1, const float* __restrict__ b1,
    const float* __restrict__ w2, const float* __restrict__ b2,
    const float* __restrict__ w3, const float* __restrict__ b3,
    const float* __restrict__ w4, const float* __restrict__ b4,
    float* __restrict__ density_out, float* __restrict__ densum_parts)
{
    int n = blockIdx.x * 256 + threadIdx.x;
    bool valid = n < NM;
    int nn = valid ? n : NM - 1;
    float a = alpha[nn], b = beta[nn];

    float h1[16], h2[16], h3[16];
    #pragma unroll
    for (int j = 0; j < 16; j++) {
        float v = fmaf(a, w1[j], fmaf(b, w1[16 + j], b1[j]));
        h1[j] = fmaxf(v, 0.f);
    }
    #pragma unroll
    for (int j = 0; j < 16; j++) {
        float v = b2[j];
        #pragma unroll
        for (int k = 0; k < 16; k++) v = fmaf(h1[k], w2[k * 16 + j], v);
        h2[j] = fmaxf(v, 0.f);
    }
    #pragma unroll
    for (int j = 0; j < 16; j++) {
        float v = b3[j];
        #pragma unroll
        for (int k = 0; k < 16; k++) v = fmaf(h2[k], w3[k * 16 + j], v);
        h3[j] = fmaxf(v, 0.f);
    }
    float v = b4[0];
    #pragma unroll
    for (int k = 0; k < 16; k++) v = fmaf(h3[k], w4[k], v);
    float d = 1.f / (1.f + __expf(-v));

    if (valid) density_out[n] = d;
    float wsum = wave_reduce_sum(valid ? d : 0.f);
    __shared__ float ws_[NWAVE];
    if ((threadIdx.x & 63) == 0) ws_[threadIdx.x >> 6] = wsum;
    __syncthreads();
    if (threadIdx.x == 0)
        densum_parts[blockIdx.x] = ws_[0] + ws_[1] + ws_[2] + ws_[3];
}

// ---- pass 1: per-(n,chunk) affine composite  s_end = A + B*s_start --------
__global__ __launch_bounds__(256) void chunk_compose_kernel(
    const float* __restrict__ x, const float* __restrict__ alpha,
    const float* __restrict__ beta,
    float* __restrict__ Abuf, float* __restrict__ Bbuf)
{
    __shared__ float xs[CH];
    int c = blockIdx.y;
    xs[threadIdx.x] = x[c * CH + threadIdx.x] * LOG2E_K;
    __syncthreads();

    int n = blockIdx.x * 256 + threadIdx.x;
    int nn = (n < NM) ? n : NM - 1;
    float ka = alpha[nn] * LOG2E_K;
    float kb = beta[nn] * LOG2E_K;

    float A = 0.f, B = 1.f;
    #pragma unroll 8
    for (int i = 0; i < CH; i++) {
        float aa, bb;
        relay_step(ka, kb, xs[i], aa, bb);
        A = fmaf(bb, A, aa);
        B *= bb;
    }
    if (n < NM) { Abuf[c * NM + n] = A; Bbuf[c * NM + n] = B; }
}

// ---- pass 2: sequential scan over the 16 chunk boundaries -----------------
__global__ __launch_bounds__(256) void chunk_scan_kernel(
    const float* __restrict__ init_raw,
    const float* __restrict__ Abuf, const float* __restrict__ Bbuf,
    float* __restrict__ sstart)
{
    int n = blockIdx.x * 256 + threadIdx.x;
    if (n >= NM) return;
    float s = tanhf(init_raw[n]);
    #pragma unroll
    for (int c = 0; c < NC; c++) {
        sstart[c * NM + n] = s;                     // state entering chunk c
        s = fmaf(Bbuf[c * NM + n], s, Abuf[c * NM + n]);
    }
}

// ---- pass 3: replay chunk, nt-store states, per-wave fused reduction ------
// LDS = 18.4 KB -> 8 blocks/CU -> ALL 1280 blocks co-resident (single round;
// the old 34.8 KB tile forced 4/CU = two rounds, 62% utilization).
// No __syncthreads in hot loop; per-wave tile, lgkmcnt-only fences.
__global__ __launch_bounds__(256) void states_kernel(
    const float* __restrict__ x, const float* __restrict__ alpha,
    const float* __restrict__ beta, const float* __restrict__ density,
    const float* __restrict__ sstart,
    float* __restrict__ states, float* __restrict__ partials)
{
    __shared__ float xs[CH];
    __shared__ float tile[NWAVE * 64 * (TPH + 1)];   // 4*64*17*4 = 17408 B

    int tid = threadIdx.x;
    int c = blockIdx.y;
    xs[tid] = x[c * CH + tid] * LOG2E_K;

    int n = blockIdx.x * 256 + tid;
    bool valid = n < NM;
    int nn = valid ? n : NM - 1;
    float ka = alpha[nn] * LOG2E_K;
    float kb = beta[nn] * LOG2E_K;
    float d  = valid ? density[n] : 0.f;
    float s  = sstart[c * NM + nn];
    __syncthreads();   // once, for xs[]; hot loop below is barrier-free

    int wv = tid >> 6, ln = tid & 63;
    int tl = ln & 15, h = ln >> 4;      // t-slot, n-group (4 groups of 16)
    float* wtile = &tile[wv * 64 * (TPH + 1)];
    float* tslot = &wtile[ln * (TPH + 1)];
    float* rowp  = states + (size_t)c * CH * NM + n;
    size_t prow  = (size_t)(blockIdx.x * NWAVE + wv) * TT + c * CH;

    for (int p = 0; p < NPH; p++) {
        #pragma unroll
        for (int j = 0; j < TPH; j++) {
            int i = p * TPH + j;
            float aa, bb;
            relay_step(ka, kb, xs[i], aa, bb);
            s = fmaf(bb, s, aa);
            if (valid) __builtin_nontemporal_store(s, rowp + (size_t)i * NM);
            tslot[j] = d * s;                 // fire-and-forget ds_write
        }
        // wait own LDS writes only (global stores stay in flight)
        asm volatile("s_waitcnt lgkmcnt(0)" ::: "memory");
        float acc = 0.f;
        #pragma unroll
        for (int k = 0; k < TPH; k++)
            acc += wtile[(h * 16 + k) * (TPH + 1) + tl];  // 2-way banks, free
        acc += __shfl_xor(acc, 16, 64);       // fold 4 n-groups
        acc += __shfl_xor(acc, 32, 64);
        if (ln < TPH) partials[prow + p * TPH + ln] = acc;
        // WAR guard before next phase overwrites the tile
        asm volatile("s_waitcnt lgkmcnt(0)" ::: "memory");
    }
}

// ---- pass 4: fold 320 wave-partials per t + 80 densum parts ---------------
__global__ __launch_bounds__(256) void finalize_kernel(
    const float* __restrict__ x, const float* __restrict__ partials,
    const float* __restrict__ densum_parts,
    const float* __restrict__ msr, const float* __restrict__ mor,
    const float* __restrict__ hsr, float* __restrict__ out)
{
    int t = blockIdx.x * 256 + threadIdx.x;
    if (t >= TT) return;
    float acc = 0.f;
    for (int r = 0; r < NPAR; r++)
        acc += partials[(size_t)r * TT + t];    // coalesced across lanes
    float dsum = 0.f;
    for (int bx = 0; bx < NBLK; bx++)
        dsum += densum_parts[bx];               // uniform -> scalar loads
    float sig_ms = 1.f / (1.f + __expf(-msr[0]));
    float sig_mo = 1.f / (1.f + __expf(-mor[0]));
    float sig_hs = 1.f / (1.f + __expf(-hsr[0]));
    float m_scale  = 10.f * sig_ms;
    float m_offset = fmaf(20.f, sig_mo, -10.f);
    float h_scale  = 10.f * sig_hs;
    float m = acc / dsum;
    out[t] = fmaf(m_scale, m, m_offset) + h_scale * x[t];
}

extern "C" void kernel_launch(void* const* d_in, const int* in_sizes, int n_in,
                              void* d_out, int out_size, void* d_ws, size_t ws_size,
                              hipStream_t stream)
{
    // setup_inputs() dict order:
    const float* x    = (const float*)d_in[0];   // [4096]
    const float* alpha= (const float*)d_in[1];   // [20301]
    const float* beta = (const float*)d_in[2];   // [20301]
    const float* init = (const float*)d_in[3];   // [20301]
    const float* msr  = (const float*)d_in[4];   // [1]
    const float* mor  = (const float*)d_in[5];   // [1]
    const float* hsr  = (const float*)d_in[6];   // [1]
    const float* w1   = (const float*)d_in[7];   // [2,16]
    const float* b1   = (const float*)d_in[8];   // [16]
    const float* w2   = (const float*)d_in[9];   // [16,16]
    const float* b2   = (const float*)d_in[10];  // [16]
    const float* w3   = (const float*)d_in[11];  // [16,16]
    const float* b3   = (const float*)d_in[12];  // [16]
    const float* w4   = (const float*)d_in[13];  // [16,1]
    const float* b4   = (const float*)d_in[14];  // [1]

    float* out     = (float*)d_out;          // [TT]
    float* density = out + TT;               // [NM]
    float* states  = density + NM;           // [TT*NM]

    // ws layout: densum_parts[80] | pad | sstart[NC*NM] | partials[NPAR*TT]
    float* densum_parts = (float*)d_ws;
    float* sstart       = densum_parts + 128;
    float* partials     = sstart + NC * NM;

    // (A,B) chunk composites stashed in the states region of d_out;
    // fully consumed by chunk_scan_kernel before states_kernel overwrites.
    float* Abuf = states;
    float* Bbuf = states + (size_t)NC * NM;

    density_kernel<<<dim3(NBLK), dim3(256), 0, stream>>>(
        alpha, beta, w1, b1, w2, b2, w3, b3, w4, b4, density, densum_parts);

    chunk_compose_kernel<<<dim3(NBLK, NC), dim3(256), 0, stream>>>(
        x, alpha, beta, Abuf, Bbuf);

    chunk_scan_kernel<<<dim3(NBLK), dim3(256), 0, stream>>>(
        init, Abuf, Bbuf, sstart);

    states_kernel<<<dim3(NBLK, NC), dim3(256), 0, stream>>>(
        x, alpha, beta, density, sstart, states, partials);

    finalize_kernel<<<dim3(TT / 256), dim3(256), 0, stream>>>(
        x, partials, densum_parts, msr, mor, hsr, out);
}

// Round 6
// 498.590 us; speedup vs baseline: 1.0277x; 1.0277x over previous
//
#include <hip/hip_runtime.h>
#include <math.h>

// Problem constants (from reference)
#define NM 20301          // mesh points (201*202/2)
#define TT 4096           // time steps
#define NC 16             // chunks over T
#define CH 256            // steps per chunk = TT/NC
#define NBLK 80           // ceil(NM/256)
#define NWAVE 4           // waves per block
#define NPAR (NBLK*NWAVE) // 320 partial rows
#define TPH 16            // t-phase width
#define NPH (CH / TPH)    // 16 phases per chunk
#define LOG2E_K 1442.69504f   // 1000 * log2(e)  (temp = 0.001)
// states starts at element offset TT+NM = 24397 ≡ 1 (mod 4) within d_out.
#define SBASE_MOD4 1

// Fused soft-relay step: one rcp instead of two:
//   r = rcp((1+e1)(1+e2)); aa = (e2-e1)*r; bb = e1*e2*r
// exp2 args clamped at 63 -> all products finite; saturation limits exact.
__device__ __forceinline__ void relay_step(float ka, float kb, float ku,
                                           float& aa, float& bb) {
    float z1 = fminf(ka - ku, 63.f);
    float z2 = fminf(ku - kb, 63.f);
    float e1 = __builtin_amdgcn_exp2f(z1);
    float e2 = __builtin_amdgcn_exp2f(z2);
    float p1 = 1.f + e1, p2 = 1.f + e2;
    float r  = __builtin_amdgcn_rcpf(p1 * p2);
    aa = (e2 - e1) * r;
    bb = (e1 * e2) * r;
}

__device__ __forceinline__ float wave_reduce_sum(float w) {
    #pragma unroll
    for (int off = 32; off > 0; off >>= 1)
        w += __shfl_down(w, off, 64);
    return w;
}

// ---------------- density MLP: [N,2] -> 16 -> 16 -> 16 -> 1 ----------------
__global__ __launch_bounds__(256) void density_kernel(
    const float* __restrict__ alpha, const float* __restrict__ beta,
    const float* __restrict__ w1, const float* __restrict__ b1,
    const float* __restrict__ w2, const float* __restrict__ b2,
    const float* __restrict__ w3, const float* __restrict__ b3,
    const float* __restrict__ w4, const float* __restrict__ b4,
    float* __restrict__ density_out, float* __restrict__ densum_parts)
{
    int n = blockIdx.x * 256 + threadIdx.x;
    bool valid = n < NM;
    int nn = valid ? n : NM - 1;
    float a = alpha[nn], b = beta[nn];

    float h1[16], h2[16], h3[16];
    #pragma unroll
    for (int j = 0; j < 16; j++) {
        float v = fmaf(a, w1[j], fmaf(b, w1[16 + j], b1[j]));
        h1[j] = fmaxf(v, 0.f);
    }
    #pragma unroll
    for (int j = 0; j < 16; j++) {
        float v = b2[j];
        #pragma unroll
        for (int k = 0; k < 16; k++) v = fmaf(h1[k], w2[k * 16 + j], v);
        h2[j] = fmaxf(v, 0.f);
    }
    #pragma unroll
    for (int j = 0; j < 16; j++) {
        float v = b3[j];
        #pragma unroll
        for (int k = 0; k < 16; k++) v = fmaf(h2[k], w3[k * 16 + j], v);
        h3[j] = fmaxf(v, 0.f);
    }
    float v = b4[0];
    #pragma unroll
    for (int k = 0; k < 16; k++) v = fmaf(h3[k], w4[k], v);
    float d = 1.f / (1.f + __expf(-v));

    if (valid) density_out[n] = d;
    float wsum = wave_reduce_sum(valid ? d : 0.f);
    __shared__ float ws_[NWAVE];
    if ((threadIdx.x & 63) == 0) ws_[threadIdx.x >> 6] = wsum;
    __syncthreads();
    if (threadIdx.x == 0)
        densum_parts[blockIdx.x] = ws_[0] + ws_[1] + ws_[2] + ws_[3];
}

// ---- pass 1: per-(n,chunk) affine composite  s_end = A + B*s_start --------
__global__ __launch_bounds__(256) void chunk_compose_kernel(
    const float* __restrict__ x, const float* __restrict__ alpha,
    const float* __restrict__ beta,
    float* __restrict__ Abuf, float* __restrict__ Bbuf)
{
    __shared__ float xs[CH];
    int c = blockIdx.y;
    xs[threadIdx.x] = x[c * CH + threadIdx.x] * LOG2E_K;
    __syncthreads();

    int n = blockIdx.x * 256 + threadIdx.x;
    int nn = (n < NM) ? n : NM - 1;
    float ka = alpha[nn] * LOG2E_K;
    float kb = beta[nn] * LOG2E_K;

    float A = 0.f, B = 1.f;
    #pragma unroll 8
    for (int i = 0; i < CH; i++) {
        float aa, bb;
        relay_step(ka, kb, xs[i], aa, bb);
        A = fmaf(bb, A, aa);
        B *= bb;
    }
    if (n < NM) { Abuf[c * NM + n] = A; Bbuf[c * NM + n] = B; }
}

// ---- pass 2: sequential scan over the 16 chunk boundaries -----------------
__global__ __launch_bounds__(256) void chunk_scan_kernel(
    const float* __restrict__ init_raw,
    const float* __restrict__ Abuf, const float* __restrict__ Bbuf,
    float* __restrict__ sstart)
{
    int n = blockIdx.x * 256 + threadIdx.x;
    if (n >= NM) return;
    float s = tanhf(init_raw[n]);
    #pragma unroll
    for (int c = 0; c < NC; c++) {
        sstart[c * NM + n] = s;                     // state entering chunk c
        s = fmaf(Bbuf[c * NM + n], s, Abuf[c * NM + n]);
    }
}

// ---- pass 3: replay chunk; stage 16 t x 64 n per-wave tile in LDS, then ---
// write each row with ALIGNED dwordx4 stores (1 KB-class bursts like the
// harness fill, which hits 6.3 TB/s, vs our former 256-B dword bursts).
// Alignment shift m_j = (t+1)&3 (states base ≡ 1 mod 4) baked into the LDS
// layout per unrolled j. d·s reduction rides the same tile reads.
// Barrier-free hot loop (per-wave tile, lgkmcnt-only fences); no nt stores.
__global__ __launch_bounds__(256) void states_kernel(
    const float* __restrict__ x, const float* __restrict__ alpha,
    const float* __restrict__ beta, const float* __restrict__ density,
    const float* __restrict__ sstart,
    float* __restrict__ states, float* __restrict__ partials)
{
    __shared__ float xs[CH];
    __shared__ __align__(16) float tile[NWAVE * TPH * 68];  // 17408 B

    int tid = threadIdx.x;
    int c = blockIdx.y;
    xs[tid] = x[c * CH + tid] * LOG2E_K;

    int n = blockIdx.x * 256 + tid;
    bool valid = n < NM;
    int nn = valid ? n : NM - 1;
    float ka = alpha[nn] * LOG2E_K;
    float kb = beta[nn] * LOG2E_K;
    float s  = sstart[c * NM + nn];
    __syncthreads();   // once, for xs[]; hot loop below is barrier-free

    int wv = tid >> 6, ln = tid & 63;
    int tg = ln >> 4,  li = ln & 15;       // row-group, lane-in-group
    int m   = (tg + 1) & 3;                // row seg misalign (t&3 == tg)
    int off = (4 - m) & 3;                 // first aligned element in row
    int A   = m ? 4 : 0;                   // aligned read base in tile row

    float* wtile = &tile[wv * TPH * 68];
    int  nb   = blockIdx.x * 256 + wv * 64;       // first n of this wave
    bool fast = (nb + 64 <= NM);                  // full wave in-bounds?

    // this lane's 4 output elements within the 64-elem row segment
    bool lane_x4 = (off == 0) || (li < 15);
    int  e0 = (off == 0) ? 4 * li : off + 4 * li; // x4 start (if lane_x4)
    float dreg[4];
    #pragma unroll
    for (int k = 0; k < 4; k++) {
        int e  = lane_x4 ? (e0 + k) : ((k < off) ? k : 60 + k);
        int nk = nb + e;
        dreg[k] = (nk < NM) ? density[nk] : 0.f;
    }

    size_t prow = (size_t)(blockIdx.x * NWAVE + wv) * TT + c * CH;

    for (int p = 0; p < NPH; p++) {
        #pragma unroll
        for (int j = 0; j < TPH; j++) {
            int i = p * TPH + j;
            float aa, bb;
            relay_step(ka, kb, xs[i], aa, bb);
            s = fmaf(bb, s, aa);
            // element ln of row j lives at j*68 + m_j + ln, m_j = ((j&3)+1)&3
            wtile[j * 68 + (((j & 3) + 1) & 3) + ln] = s;
            if (!fast && valid)                        // edge wave: scalar
                states[(size_t)(c * CH + i) * NM + n] = s;
        }
        asm volatile("s_waitcnt lgkmcnt(0)" ::: "memory");  // tile ready

        #pragma unroll
        for (int r = 0; r < 4; r++) {
            int j = tg + 4 * r;                 // j&3 == tg for all r
            int t = c * CH + p * TPH + j;
            size_t g0 = (size_t)t * NM + nb;    // row-segment global base
            float v0, v1, v2, v3;
            if (lane_x4) {
                const float4 vv = *(const float4*)&wtile[j * 68 + A + 4 * li];
                v0 = vv.x; v1 = vv.y; v2 = vv.z; v3 = vv.w;
                if (fast) *(float4*)(states + g0 + e0) = vv;  // 16B aligned
            } else {
                // boundary lane (off>0, li==15): head+tail scattered elems
                #pragma unroll
                for (int k = 0; k < 4; k++) {
                    int e = (k < off) ? k : 60 + k;
                    float sv = wtile[j * 68 + m + e];
                    if (k == 0) v0 = sv; else if (k == 1) v1 = sv;
                    else if (k == 2) v2 = sv; else v3 = sv;
                    if (fast) states[g0 + e] = sv;
                }
            }
            // fused d·s reduction over this row's 64 elements
            float q = fmaf(v0, dreg[0], fmaf(v1, dreg[1],
                      fmaf(v2, dreg[2], v3 * dreg[3])));
            q += __shfl_xor(q, 1);
            q += __shfl_xor(q, 2);
            q += __shfl_xor(q, 4);
            q += __shfl_xor(q, 8);
            if (li == 0) partials[prow + p * TPH + j] = q;
        }
        asm volatile("s_waitcnt lgkmcnt(0)" ::: "memory");  // WAR on tile
    }
}

// ---- pass 4: fold 320 wave-partials per t + 80 densum parts ---------------
__global__ __launch_bounds__(256) void finalize_kernel(
    const float* __restrict__ x, const float* __restrict__ partials,
    const float* __restrict__ densum_parts,
    const float* __restrict__ msr, const float* __restrict__ mor,
    const float* __restrict__ hsr, float* __restrict__ out)
{
    int t = blockIdx.x * 256 + threadIdx.x;
    if (t >= TT) return;
    float acc = 0.f;
    for (int r = 0; r < NPAR; r++)
        acc += partials[(size_t)r * TT + t];    // coalesced across lanes
    float dsum = 0.f;
    for (int bx = 0; bx < NBLK; bx++)
        dsum += densum_parts[bx];               // uniform -> scalar loads
    float sig_ms = 1.f / (1.f + __expf(-msr[0]));
    float sig_mo = 1.f / (1.f + __expf(-mor[0]));
    float sig_hs = 1.f / (1.f + __expf(-hsr[0]));
    float m_scale  = 10.f * sig_ms;
    float m_offset = fmaf(20.f, sig_mo, -10.f);
    float h_scale  = 10.f * sig_hs;
    float m = acc / dsum;
    out[t] = fmaf(m_scale, m, m_offset) + h_scale * x[t];
}

extern "C" void kernel_launch(void* const* d_in, const int* in_sizes, int n_in,
                              void* d_out, int out_size, void* d_ws, size_t ws_size,
                              hipStream_t stream)
{
    // setup_inputs() dict order:
    const float* x    = (const float*)d_in[0];   // [4096]
    const float* alpha= (const float*)d_in[1];   // [20301]
    const float* beta = (const float*)d_in[2];   // [20301]
    const float* init = (const float*)d_in[3];   // [20301]
    const float* msr  = (const float*)d_in[4];   // [1]
    const float* mor  = (const float*)d_in[5];   // [1]
    const float* hsr  = (const float*)d_in[6];   // [1]
    const float* w1   = (const float*)d_in[7];   // [2,16]
    const float* b1   = (const float*)d_in[8];   // [16]
    const float* w2   = (const float*)d_in[9];   // [16,16]
    const float* b2   = (const float*)d_in[10];  // [16]
    const float* w3   = (const float*)d_in[11];  // [16,16]
    const float* b3   = (const float*)d_in[12];  // [16]
    const float* w4   = (const float*)d_in[13];  // [16,1]
    const float* b4   = (const float*)d_in[14];  // [1]

    float* out     = (float*)d_out;          // [TT]
    float* density = out + TT;               // [NM]
    float* states  = density + NM;           // [TT*NM], elem off 24397 ≡1 mod 4

    // ws layout: densum_parts[80] | pad | sstart[NC*NM] | partials[NPAR*TT]
    float* densum_parts = (float*)d_ws;
    float* sstart       = densum_parts + 128;
    float* partials     = sstart + NC * NM;

    // (A,B) chunk composites stashed in the states region of d_out;
    // fully consumed by chunk_scan_kernel before states_kernel overwrites.
    float* Abuf = states;
    float* Bbuf = states + (size_t)NC * NM;

    density_kernel<<<dim3(NBLK), dim3(256), 0, stream>>>(
        alpha, beta, w1, b1, w2, b2, w3, b3, w4, b4, density, densum_parts);

    chunk_compose_kernel<<<dim3(NBLK, NC), dim3(256), 0, stream>>>(
        x, alpha, beta, Abuf, Bbuf);

    chunk_scan_kernel<<<dim3(NBLK), dim3(256), 0, stream>>>(
        init, Abuf, Bbuf, sstart);

    states_kernel<<<dim3(NBLK, NC), dim3(256), 0, stream>>>(
        x, alpha, beta, density, sstart, states, partials);

    finalize_kernel<<<dim3(TT / 256), dim3(256), 0, stream>>>(
        x, partials, densum_parts, msr, mor, hsr, out);
}

// Round 7
// 477.225 us; speedup vs baseline: 1.0737x; 1.0448x over previous
//
#include <hip/hip_runtime.h>
#include <math.h>

// Problem constants (from reference)
#define NM 20301          // mesh points (201*202/2)
#define TT 4096           // time steps
#define NC 16             // chunks over T
#define CH 256            // steps per chunk = TT/NC
#define NBLK 80           // ceil(NM/256)
#define NWAVE 4           // waves per block
#define NPAR (NBLK*NWAVE) // 320 partial rows
#define TPH 16            // t-phase width (18.4 KB LDS -> 8 blocks/CU)
#define NPH (CH / TPH)    // 16 phases per chunk
#define LOG2E_K 1442.69504f   // 1000 * log2(e)  (temp = 0.001)
// Saturation cutoff in log2-scaled units: |w|>=26 <=> |z|>=18.0 natural.
// z>17.33 -> fp32 sigmoid == 1.0 EXACTLY; z<-18 -> sigmoid < 1.5e-8 ~= 0.
#define WNEAR 26.0f

// Fused soft-relay step (slow path): one rcp instead of two:
//   r = rcp((1+e1)(1+e2)); aa = (e2-e1)*r; bb = e1*e2*r
// exp2 args clamped at 63 -> products finite; saturation limits exact.
__device__ __forceinline__ void relay_step(float ka, float kb, float ku,
                                           float& aa, float& bb) {
    float z1 = fminf(ka - ku, 63.f);
    float z2 = fminf(ku - kb, 63.f);
    float e1 = __builtin_amdgcn_exp2f(z1);
    float e2 = __builtin_amdgcn_exp2f(z2);
    float p1 = 1.f + e1, p2 = 1.f + e2;
    float r  = __builtin_amdgcn_rcpf(p1 * p2);
    aa = (e2 - e1) * r;
    bb = (e1 * e2) * r;
}

__device__ __forceinline__ float wave_reduce_sum(float w) {
    #pragma unroll
    for (int off = 32; off > 0; off >>= 1)
        w += __shfl_down(w, off, 64);
    return w;
}

// ---------------- density MLP: [N,2] -> 16 -> 16 -> 16 -> 1 ----------------
__global__ __launch_bounds__(256) void density_kernel(
    const float* __restrict__ alpha, const float* __restrict__ beta,
    const float* __restrict__ w1, const float* __restrict__ b1,
    const float* __restrict__ w2, const float* __restrict__ b2,
    const float* __restrict__ w3, const float* __restrict__ b3,
    const float* __restrict__ w4, const float* __restrict__ b4,
    float* __restrict__ density_out, float* __restrict__ densum_parts)
{
    int n = blockIdx.x * 256 + threadIdx.x;
    bool valid = n < NM;
    int nn = valid ? n : NM - 1;
    float a = alpha[nn], b = beta[nn];

    float h1[16], h2[16], h3[16];
    #pragma unroll
    for (int j = 0; j < 16; j++) {
        float v = fmaf(a, w1[j], fmaf(b, w1[16 + j], b1[j]));
        h1[j] = fmaxf(v, 0.f);
    }
    #pragma unroll
    for (int j = 0; j < 16; j++) {
        float v = b2[j];
        #pragma unroll
        for (int k = 0; k < 16; k++) v = fmaf(h1[k], w2[k * 16 + j], v);
        h2[j] = fmaxf(v, 0.f);
    }
    #pragma unroll
    for (int j = 0; j < 16; j++) {
        float v = b3[j];
        #pragma unroll
        for (int k = 0; k < 16; k++) v = fmaf(h2[k], w3[k * 16 + j], v);
        h3[j] = fmaxf(v, 0.f);
    }
    float v = b4[0];
    #pragma unroll
    for (int k = 0; k < 16; k++) v = fmaf(h3[k], w4[k], v);
    float d = 1.f / (1.f + __expf(-v));

    if (valid) density_out[n] = d;
    float wsum = wave_reduce_sum(valid ? d : 0.f);
    __shared__ float ws_[NWAVE];
    if ((threadIdx.x & 63) == 0) ws_[threadIdx.x >> 6] = wsum;
    __syncthreads();
    if (threadIdx.x == 0)
        densum_parts[blockIdx.x] = ws_[0] + ws_[1] + ws_[2] + ws_[3];
}

// ---- pass 1: per-(n,chunk) affine composite  s_end = A + B*s_start --------
// Fast path: both sigmoids saturated (the common case at temp=0.001) ->
// switch-up: (A,B)=(1,0); switch-down: (A,B)=(-1,0); hold: no-op.
__global__ __launch_bounds__(256) void chunk_compose_kernel(
    const float* __restrict__ x, const float* __restrict__ alpha,
    const float* __restrict__ beta,
    float* __restrict__ Abuf, float* __restrict__ Bbuf)
{
    __shared__ float xs[CH];
    int c = blockIdx.y;
    xs[threadIdx.x] = x[c * CH + threadIdx.x] * LOG2E_K;
    __syncthreads();

    int n = blockIdx.x * 256 + threadIdx.x;
    int nn = (n < NM) ? n : NM - 1;
    float ka = alpha[nn] * LOG2E_K;
    float kb = beta[nn] * LOG2E_K;

    float A = 0.f, B = 1.f;
    for (int p = 0; p < NPH; p++) {
        float xr[TPH];
        #pragma unroll
        for (int j = 0; j < TPH; j++) xr[j] = xs[p * TPH + j];  // batched
        #pragma unroll
        for (int j = 0; j < TPH; j++) {
            float ku = xr[j];
            float w1 = ka - ku, w2 = ku - kb;
            bool nearb = fminf(fabsf(w1), fabsf(w2)) < WNEAR;
            if (__any(nearb)) {                  // wave-uniform branch
                float aa, bb;
                relay_step(ka, kb, ku, aa, bb);
                A = fmaf(bb, A, aa);
                B *= bb;
            } else {
                bool swu = w1 < 0.f, swd = w2 < 0.f;
                A = swu ? 1.f : (swd ? -1.f : A);
                B = (swu || swd) ? 0.f : B;
            }
        }
    }
    if (n < NM) { Abuf[c * NM + n] = A; Bbuf[c * NM + n] = B; }
}

// ---- pass 2: sequential scan over the 16 chunk boundaries -----------------
__global__ __launch_bounds__(256) void chunk_scan_kernel(
    const float* __restrict__ init_raw,
    const float* __restrict__ Abuf, const float* __restrict__ Bbuf,
    float* __restrict__ sstart)
{
    int n = blockIdx.x * 256 + threadIdx.x;
    if (n >= NM) return;
    float s = tanhf(init_raw[n]);
    #pragma unroll
    for (int c = 0; c < NC; c++) {
        sstart[c * NM + n] = s;                     // state entering chunk c
        s = fmaf(Bbuf[c * NM + n], s, Abuf[c * NM + n]);
    }
}

// ---- pass 3: replay chunk with saturated fast path, store states, --------
// per-wave fused d*s reduction (barrier-free hot loop, lgkmcnt-only fences).
__global__ __launch_bounds__(256) void states_kernel(
    const float* __restrict__ x, const float* __restrict__ alpha,
    const float* __restrict__ beta, const float* __restrict__ density,
    const float* __restrict__ sstart,
    float* __restrict__ states, float* __restrict__ partials)
{
    __shared__ float xs[CH];
    __shared__ float tile[NWAVE * 64 * (TPH + 1)];   // 17408 B

    int tid = threadIdx.x;
    int c = blockIdx.y;
    xs[tid] = x[c * CH + tid] * LOG2E_K;

    int n = blockIdx.x * 256 + tid;
    bool valid = n < NM;
    int nn = valid ? n : NM - 1;
    float ka = alpha[nn] * LOG2E_K;
    float kb = beta[nn] * LOG2E_K;
    float d  = valid ? density[n] : 0.f;
    float s  = sstart[c * NM + nn];
    __syncthreads();   // once, for xs[]; hot loop below is barrier-free

    int wv = tid >> 6, ln = tid & 63;
    int tl = ln & 15, h = ln >> 4;      // t-slot, n-group (4 groups of 16)
    float* wtile = &tile[wv * 64 * (TPH + 1)];
    float* tslot = &wtile[ln * (TPH + 1)];
    float* rowp  = states + (size_t)c * CH * NM + n;
    size_t prow  = (size_t)(blockIdx.x * NWAVE + wv) * TT + c * CH;

    for (int p = 0; p < NPH; p++) {
        float xr[TPH];
        #pragma unroll
        for (int j = 0; j < TPH; j++) xr[j] = xs[p * TPH + j];  // batched
        #pragma unroll
        for (int j = 0; j < TPH; j++) {
            float ku = xr[j];
            float w1 = ka - ku, w2 = ku - kb;
            bool nearb = fminf(fabsf(w1), fabsf(w2)) < WNEAR;
            if (__any(nearb)) {                  // wave-uniform branch
                float aa, bb;
                relay_step(ka, kb, ku, aa, bb);
                s = fmaf(bb, s, aa);
            } else {
                s = (w1 < 0.f) ? 1.f : ((w2 < 0.f) ? -1.f : s);
            }
            if (valid) rowp[(size_t)(p * TPH + j) * NM] = s;
            tslot[j] = d * s;                 // fire-and-forget ds_write
        }
        // wait own LDS writes only (global stores stay in flight)
        asm volatile("s_waitcnt lgkmcnt(0)" ::: "memory");
        float acc = 0.f;
        #pragma unroll
        for (int k = 0; k < TPH; k++)
            acc += wtile[(h * 16 + k) * (TPH + 1) + tl];  // 2-way banks, free
        acc += __shfl_xor(acc, 16, 64);       // fold 4 n-groups
        acc += __shfl_xor(acc, 32, 64);
        if (ln < TPH) partials[prow + p * TPH + ln] = acc;
        // WAR guard before next phase overwrites the tile
        asm volatile("s_waitcnt lgkmcnt(0)" ::: "memory");
    }
}

// ---- pass 4: fold 320 wave-partials per t + 80 densum parts ---------------
__global__ __launch_bounds__(256) void finalize_kernel(
    const float* __restrict__ x, const float* __restrict__ partials,
    const float* __restrict__ densum_parts,
    const float* __restrict__ msr, const float* __restrict__ mor,
    const float* __restrict__ hsr, float* __restrict__ out)
{
    int t = blockIdx.x * 256 + threadIdx.x;
    if (t >= TT) return;
    float acc = 0.f;
    for (int r = 0; r < NPAR; r++)
        acc += partials[(size_t)r * TT + t];    // coalesced across lanes
    float dsum = 0.f;
    for (int bx = 0; bx < NBLK; bx++)
        dsum += densum_parts[bx];               // uniform -> scalar loads
    float sig_ms = 1.f / (1.f + __expf(-msr[0]));
    float sig_mo = 1.f / (1.f + __expf(-mor[0]));
    float sig_hs = 1.f / (1.f + __expf(-hsr[0]));
    float m_scale  = 10.f * sig_ms;
    float m_offset = fmaf(20.f, sig_mo, -10.f);
    float h_scale  = 10.f * sig_hs;
    float m = acc / dsum;
    out[t] = fmaf(m_scale, m, m_offset) + h_scale * x[t];
}

extern "C" void kernel_launch(void* const* d_in, const int* in_sizes, int n_in,
                              void* d_out, int out_size, void* d_ws, size_t ws_size,
                              hipStream_t stream)
{
    // setup_inputs() dict order:
    const float* x    = (const float*)d_in[0];   // [4096]
    const float* alpha= (const float*)d_in[1];   // [20301]
    const float* beta = (const float*)d_in[2];   // [20301]
    const float* init = (const float*)d_in[3];   // [20301]
    const float* msr  = (const float*)d_in[4];   // [1]
    const float* mor  = (const float*)d_in[5];   // [1]
    const float* hsr  = (const float*)d_in[6];   // [1]
    const float* w1   = (const float*)d_in[7];   // [2,16]
    const float* b1   = (const float*)d_in[8];   // [16]
    const float* w2   = (const float*)d_in[9];   // [16,16]
    const float* b2   = (const float*)d_in[10];  // [16]
    const float* w3   = (const float*)d_in[11];  // [16,16]
    const float* b3   = (const float*)d_in[12];  // [16]
    const float* w4   = (const float*)d_in[13];  // [16,1]
    const float* b4   = (const float*)d_in[14];  // [1]

    float* out     = (float*)d_out;          // [TT]
    float* density = out + TT;               // [NM]
    float* states  = density + NM;           // [TT*NM]

    // ws layout: densum_parts[80] | pad | sstart[NC*NM] | partials[NPAR*TT]
    float* densum_parts = (float*)d_ws;
    float* sstart       = densum_parts + 128;
    float* partials     = sstart + NC * NM;

    // (A,B) chunk composites stashed in the states region of d_out;
    // fully consumed by chunk_scan_kernel before states_kernel overwrites.
    float* Abuf = states;
    float* Bbuf = states + (size_t)NC * NM;

    density_kernel<<<dim3(NBLK), dim3(256), 0, stream>>>(
        alpha, beta, w1, b1, w2, b2, w3, b3, w4, b4, density, densum_parts);

    chunk_compose_kernel<<<dim3(NBLK, NC), dim3(256), 0, stream>>>(
        x, alpha, beta, Abuf, Bbuf);

    chunk_scan_kernel<<<dim3(NBLK), dim3(256), 0, stream>>>(
        init, Abuf, Bbuf, sstart);

    states_kernel<<<dim3(NBLK, NC), dim3(256), 0, stream>>>(
        x, alpha, beta, density, sstart, states, partials);

    finalize_kernel<<<dim3(TT / 256), dim3(256), 0, stream>>>(
        x, partials, densum_parts, msr, mor, hsr, out);
}